// Round 4
// baseline (629.382 us; speedup 1.0000x reference)
//
#include <hip/hip_runtime.h>
#include <hip/hip_bf16.h>
#include <stdint.h>

typedef unsigned short u16;
typedef __attribute__((ext_vector_type(8))) __bf16 bf16x8;
typedef __attribute__((ext_vector_type(4))) float f32x4;
typedef __attribute__((ext_vector_type(16))) float f32x16;
typedef __attribute__((ext_vector_type(8))) u16 us8;
typedef __attribute__((ext_vector_type(4))) unsigned u32x4;

#define QSCALE 0.08838834764831843f

__device__ __forceinline__ u16 f2bf(float f) {
  unsigned u = __float_as_uint(f);
  u += 0x7fffu + ((u >> 16) & 1u);
  return (u16)(u >> 16);
}
__device__ __forceinline__ float bf2f(u16 h) {
  return __uint_as_float(((unsigned)h) << 16);
}
// async global->LDS, 16B per lane. lds dst must be wave-uniform base (HW adds lane*16).
__device__ __forceinline__ void gload16(const void* g, void* l) {
  __builtin_amdgcn_global_load_lds(
      (const __attribute__((address_space(1))) unsigned int*)g,
      (__attribute__((address_space(3))) unsigned int*)l, 16, 0, 0);
}
__device__ __forceinline__ unsigned sx32(unsigned v) {
  return (unsigned)__shfl_xor((int)v, 32, 64);
}

// ---------------------------------------------------------------------------
// P1: weight prep -> bf16 [outcol][k] layouts.
// WCT layout: [m][3072][2048] where cols 0-2047=Q, 2048-2559=K_sum, 2560-3071=V_sum.
// WOT layout: [m][2048][2048].
// ---------------------------------------------------------------------------
__global__ __launch_bounds__(256) void wprep(
    const float* __restrict__ Wq, const float* __restrict__ Wk,
    const float* __restrict__ Wv, const float* __restrict__ Wo,
    u16* __restrict__ WCT, u16* __restrict__ WOT) {
  const int sec = blockIdx.z;
  const float* s0;
  const float* s1 = nullptr;
  u16* dst;
  int N;
  switch (sec) {
    case 0: s0 = Wq;                 dst = WCT;                    N = 2048; break;
    case 1: s0 = Wq + 2048*2048;     dst = WCT + (size_t)3072*2048; N = 2048; break;
    case 2: s0 = Wk;                 s1 = Wk + 2048*512;  dst = WCT + (size_t)2048*2048; N = 512; break;
    case 3: s0 = Wk + 2*2048*512;    s1 = Wk + 3*2048*512; dst = WCT + (size_t)5120*2048; N = 512; break;
    case 4: s0 = Wv;                 s1 = Wv + 2048*512;  dst = WCT + (size_t)2560*2048; N = 512; break;
    case 5: s0 = Wv + 2*2048*512;    s1 = Wv + 3*2048*512; dst = WCT + (size_t)5632*2048; N = 512; break;
    case 6: s0 = Wo;                 dst = WOT;                    N = 2048; break;
    default: s0 = Wo + 2048*2048;    dst = WOT + (size_t)2048*2048; N = 2048; break;
  }
  const int n0 = blockIdx.x * 32;
  if (n0 >= N) return;
  const int k0 = blockIdx.y * 32;
  __shared__ float tile[32][33];
  const int tx = threadIdx.x & 31, ty = threadIdx.x >> 5;
#pragma unroll
  for (int i = 0; i < 4; ++i) {
    int k = k0 + ty + 8 * i;
    float v = s0[(size_t)k * N + n0 + tx];
    if (s1) v += s1[(size_t)k * N + n0 + tx];
    tile[ty + 8 * i][tx] = v;
  }
  __syncthreads();
#pragma unroll
  for (int i = 0; i < 4; ++i) {
    int n = n0 + ty + 8 * i;
    dst[(size_t)n * 2048 + k0 + tx] = f2bf(tile[tx][ty + 8 * i]);
  }
}

// ---------------------------------------------------------------------------
// P2: x f32 -> bf16
// ---------------------------------------------------------------------------
__global__ __launch_bounds__(256) void xcast(const float* __restrict__ x,
                                             u16* __restrict__ Xbf) {
  size_t base = ((size_t)blockIdx.x * 256 + threadIdx.x) * 8;
  float4 a = *(const float4*)&x[base];
  float4 c = *(const float4*)&x[base + 4];
  us8 o;
  o[0] = f2bf(a.x); o[1] = f2bf(a.y); o[2] = f2bf(a.z); o[3] = f2bf(a.w);
  o[4] = f2bf(c.x); o[5] = f2bf(c.y); o[6] = f2bf(c.z); o[7] = f2bf(c.w);
  *(us8*)&Xbf[base] = o;
}

// ---------------------------------------------------------------------------
// S1: count modality-0 tokens; init scatter counters. cnt[0]=n0, cnt[1..2]=0.
// ---------------------------------------------------------------------------
__global__ __launch_bounds__(256) void scount(const int* __restrict__ mid,
                                              int* __restrict__ cnt) {
  __shared__ int sh[256];
  int s = 0;
  for (int i = threadIdx.x; i < 4096; i += 256) s += (mid[i] == 0);
  sh[threadIdx.x] = s;
  __syncthreads();
  for (int o = 128; o; o >>= 1) {
    if (threadIdx.x < o) sh[threadIdx.x] += sh[threadIdx.x + o];
    __syncthreads();
  }
  if (threadIdx.x == 0) { cnt[0] = sh[0]; cnt[1] = 0; cnt[2] = 0; }
}

// ---------------------------------------------------------------------------
// S2: scatter tokens into modality buckets. perm[sorted]=token, inv[token]=sorted.
// Intra-bucket order nondeterministic (atomics) — per-token results are
// position-invariant so the final output is unaffected.
// ---------------------------------------------------------------------------
__global__ __launch_bounds__(256) void sscatter(const int* __restrict__ mid,
                                                int* __restrict__ cnt,
                                                int* __restrict__ perm,
                                                int* __restrict__ inv) {
  int t = blockIdx.x * 256 + threadIdx.x;
  int m = mid[t];
  int base = m ? cnt[0] : 0;
  int pos = base + atomicAdd(&cnt[1 + m], 1);
  perm[pos] = t;
  inv[t] = pos;
}

// ---------------------------------------------------------------------------
// G1: QKV projection over sorted tokens. C[sorted_row][3072] = X[perm[row]] @ W[seg]^T.
// grid (24 col-tiles, 66 row-tiles): y<33 -> segment 0 (rows [0,n0)), else seg 1.
// m97 structure, A-row indirection via perm (per-lane global src; LDS dest linear).
// ---------------------------------------------------------------------------
__global__ __launch_bounds__(256) void gemm_qkv(
    const u16* __restrict__ A, const u16* __restrict__ W, u16* __restrict__ Cq,
    const int* __restrict__ cnt, const int* __restrict__ perm) {
  __shared__ u16 As[128 * 32];
  __shared__ u16 Bs[128 * 32];
  const int n0 = cnt[0];
  const int nbx = 24, nwg = 24 * 66;
  int bid = blockIdx.y * nbx + blockIdx.x;
  const int q8 = nwg >> 3;
  int swz = (bid & 7) * q8 + (bid >> 3);
  const int bx = swz % nbx, by = swz / nbx;
  int seg, r0, rend;
  if (by < 33) { seg = 0; r0 = by * 128; rend = n0; }
  else         { seg = 1; r0 = n0 + (by - 33) * 128; rend = 4096; }
  if (r0 >= rend) return;
  const int col0 = bx * 128;
  const int tid = threadIdx.x, wid = tid >> 6, lane = tid & 63;
  const int lr = lane & 15, lg = lane >> 4;
  const int wr = wid >> 1, wc = wid & 1;
  const u16* W0 = W + ((size_t)seg * 3072 + col0) * 2048;
  const int ra = tid >> 2, gA = tid & 3;
  int ti0 = r0 + ra;      if (ti0 > rend - 1) ti0 = rend - 1;
  int ti1 = r0 + 64 + ra; if (ti1 > rend - 1) ti1 = rend - 1;
  const u16* Ar0 = A + (size_t)perm[ti0] * 2048;
  const u16* Ar1 = A + (size_t)perm[ti1] * 2048;
  const u16* Br0 = W0 + (size_t)ra * 2048;
  const u16* Br1 = W0 + (size_t)(64 + ra) * 2048;

  f32x4 acc[4][4];
#pragma unroll
  for (int m = 0; m < 4; ++m)
#pragma unroll
    for (int n = 0; n < 4; ++n)
#pragma unroll
      for (int r = 0; r < 4; ++r) acc[m][n][r] = 0.f;

  for (int k0 = 0; k0 < 2048; k0 += 32) {
    gload16(Ar0 + k0 + gA * 8, &As[(0 * 256 + wid * 64) * 8]);
    gload16(Br0 + k0 + gA * 8, &Bs[(0 * 256 + wid * 64) * 8]);
    gload16(Ar1 + k0 + gA * 8, &As[(1 * 256 + wid * 64) * 8]);
    gload16(Br1 + k0 + gA * 8, &Bs[(1 * 256 + wid * 64) * 8]);
    __syncthreads();
    bf16x8 af[4], bfr[4];
#pragma unroll
    for (int m = 0; m < 4; ++m)
      af[m] = *(const bf16x8*)&As[(64 * wr + 16 * m + lr) * 32 + 8 * lg];
#pragma unroll
    for (int n = 0; n < 4; ++n)
      bfr[n] = *(const bf16x8*)&Bs[(64 * wc + 16 * n + lr) * 32 + 8 * lg];
#pragma unroll
    for (int m = 0; m < 4; ++m)
#pragma unroll
      for (int n = 0; n < 4; ++n)
        acc[m][n] = __builtin_amdgcn_mfma_f32_16x16x32_bf16(af[m], bfr[n], acc[m][n], 0, 0, 0);
    __syncthreads();
  }
#pragma unroll
  for (int m = 0; m < 4; ++m)
#pragma unroll
    for (int n = 0; n < 4; ++n)
#pragma unroll
      for (int r = 0; r < 4; ++r) {
        int grow = r0 + 64 * wr + 16 * m + 4 * lg + r;
        if (grow < rend) {
          int gcol = col0 + 64 * wc + 16 * n + lr;
          Cq[(size_t)grow * 3072 + gcol] = f2bf(acc[m][n][r]);
        }
      }
}

// ---------------------------------------------------------------------------
// G2: O-projection over sorted tokens, N=2048 (single modality per segment).
// Stores f32 directly to out[token] (scatter via perm).
// ---------------------------------------------------------------------------
__global__ __launch_bounds__(256) void gemm_out(
    const u16* __restrict__ A, const u16* __restrict__ W,
    const int* __restrict__ cnt, const int* __restrict__ perm,
    float* __restrict__ out) {
  __shared__ u16 As[128 * 32];
  __shared__ u16 Bs[128 * 32];
  const int n0 = cnt[0];
  const int nbx = 16, nwg = 16 * 66;
  int bid = blockIdx.y * nbx + blockIdx.x;
  const int q8 = nwg >> 3;
  int swz = (bid & 7) * q8 + (bid >> 3);
  const int bx = swz % nbx, by = swz / nbx;
  int seg, r0, rend;
  if (by < 33) { seg = 0; r0 = by * 128; rend = n0; }
  else         { seg = 1; r0 = n0 + (by - 33) * 128; rend = 4096; }
  if (r0 >= rend) return;
  const int col0 = bx * 128;
  const int tid = threadIdx.x, wid = tid >> 6, lane = tid & 63;
  const int lr = lane & 15, lg = lane >> 4;
  const int wr = wid >> 1, wc = wid & 1;
  const u16* W0 = W + ((size_t)seg * 2048 + col0) * 2048;
  const int ra = tid >> 2, gA = tid & 3;
  int ti0 = r0 + ra;      if (ti0 > rend - 1) ti0 = rend - 1;
  int ti1 = r0 + 64 + ra; if (ti1 > rend - 1) ti1 = rend - 1;
  const u16* Ar0 = A + (size_t)perm[ti0] * 2048;
  const u16* Ar1 = A + (size_t)perm[ti1] * 2048;
  const u16* Br0 = W0 + (size_t)ra * 2048;
  const u16* Br1 = W0 + (size_t)(64 + ra) * 2048;

  f32x4 acc[4][4];
#pragma unroll
  for (int m = 0; m < 4; ++m)
#pragma unroll
    for (int n = 0; n < 4; ++n)
#pragma unroll
      for (int r = 0; r < 4; ++r) acc[m][n][r] = 0.f;

  for (int k0 = 0; k0 < 2048; k0 += 32) {
    gload16(Ar0 + k0 + gA * 8, &As[(0 * 256 + wid * 64) * 8]);
    gload16(Br0 + k0 + gA * 8, &Bs[(0 * 256 + wid * 64) * 8]);
    gload16(Ar1 + k0 + gA * 8, &As[(1 * 256 + wid * 64) * 8]);
    gload16(Br1 + k0 + gA * 8, &Bs[(1 * 256 + wid * 64) * 8]);
    __syncthreads();
    bf16x8 af[4], bfr[4];
#pragma unroll
    for (int m = 0; m < 4; ++m)
      af[m] = *(const bf16x8*)&As[(64 * wr + 16 * m + lr) * 32 + 8 * lg];
#pragma unroll
    for (int n = 0; n < 4; ++n)
      bfr[n] = *(const bf16x8*)&Bs[(64 * wc + 16 * n + lr) * 32 + 8 * lg];
#pragma unroll
    for (int m = 0; m < 4; ++m)
#pragma unroll
      for (int n = 0; n < 4; ++n)
        acc[m][n] = __builtin_amdgcn_mfma_f32_16x16x32_bf16(af[m], bfr[n], acc[m][n], 0, 0, 0);
    __syncthreads();
  }
#pragma unroll
  for (int m = 0; m < 4; ++m)
#pragma unroll
    for (int r = 0; r < 4; ++r) {
      int grow = r0 + 64 * wr + 16 * m + 4 * lg + r;
      if (grow < rend) {
        int tok = perm[grow];
#pragma unroll
        for (int n = 0; n < 4; ++n) {
          int gcol = col0 + 64 * wc + 16 * n + lr;
          out[(size_t)tok * 2048 + gcol] = acc[m][n][r];
        }
      }
    }
}

// ---------------------------------------------------------------------------
// A0: RoPE for Q (scaled) and K over sorted rows; writes token-order layouts.
// ---------------------------------------------------------------------------
__global__ __launch_bounds__(256) void rope_select(
    const u16* __restrict__ QKVs, const int* __restrict__ perm,
    const float* __restrict__ fc, u16* __restrict__ Qr, u16* __restrict__ Kr) {
  const int i = blockIdx.x;
  const int t = perm[i];
  const int b = t >> 11, s = t & 2047;
  __shared__ float Fs[256];
  Fs[threadIdx.x] = fc[(size_t)s * 256 + threadIdx.x];
  __syncthreads();
  const int tid = threadIdx.x;
  {  // Q: 1024 pairs, 4/thread
    int p0 = tid * 4;
    int h = p0 >> 6, ph0 = p0 & 63;
    const u16* src = QKVs + (size_t)i * 3072 + h * 128 + 2 * ph0;
    us8 v = *(const us8*)src;
    us8 o;
#pragma unroll
    for (int j = 0; j < 4; ++j) {
      float x0 = bf2f(v[2 * j]), x1 = bf2f(v[2 * j + 1]);
      const float* F = &Fs[(ph0 + j) * 4];
      o[2 * j]     = f2bf((x0 * F[0] + x1 * F[2]) * QSCALE);
      o[2 * j + 1] = f2bf((x0 * F[1] + x1 * F[3]) * QSCALE);
    }
    *(us8*)(Qr + (((size_t)(b * 16 + h) * 2048) + s) * 128 + 2 * ph0) = o;
  }
  if (tid < 64) {  // K: 256 pairs, 4/thread
    int p0 = tid * 4;
    int kh = p0 >> 6, ph0 = p0 & 63;
    const u16* src = QKVs + (size_t)i * 3072 + 2048 + kh * 128 + 2 * ph0;
    us8 v = *(const us8*)src;
    us8 o;
#pragma unroll
    for (int j = 0; j < 4; ++j) {
      float x0 = bf2f(v[2 * j]), x1 = bf2f(v[2 * j + 1]);
      const float* F = &Fs[(ph0 + j) * 4];
      o[2 * j]     = f2bf(x0 * F[0] + x1 * F[2]);
      o[2 * j + 1] = f2bf(x0 * F[1] + x1 * F[3]);
    }
    *(us8*)(Kr + (((size_t)(b * 4 + kh) * 2048) + s) * 128 + 2 * ph0) = o;
  }
}

// ---------------------------------------------------------------------------
// A1: V transpose -> Vt [b][kv][d][s] bf16 (reads sorted QKVs rows via inv)
// ---------------------------------------------------------------------------
__global__ __launch_bounds__(256) void vtrans(
    const u16* __restrict__ QKVs, const int* __restrict__ inv, u16* __restrict__ Vt) {
  __shared__ u16 tilebuf[32][34];
  const int s0 = blockIdx.x * 32, d0 = blockIdx.y * 32, b = blockIdx.z;
  const int tx = threadIdx.x & 31, ty = threadIdx.x >> 5;
#pragma unroll
  for (int i = 0; i < 4; ++i) {
    int s = s0 + ty + 8 * i;
    int row = inv[b * 2048 + s];
    tilebuf[ty + 8 * i][tx] = QKVs[(size_t)row * 3072 + 2560 + d0 + tx];
  }
  __syncthreads();
#pragma unroll
  for (int i = 0; i < 4; ++i) {
    int d = d0 + ty + 8 * i;
    Vt[(((size_t)(b * 4 + (d >> 7)) * 128) + (d & 127)) * 2048 + s0 + tx] =
        tilebuf[tx][ty + 8 * i];
  }
}

// ---------------------------------------------------------------------------
// A2: flash attention (unchanged from R2): 8 waves x 32 q-rows, 32x32x16 MFMA,
// swapped QK^T, O^T PV, K/V LDS double-buffer, XOR-swizzled b128.
// ---------------------------------------------------------------------------
__global__ __launch_bounds__(512, 2) void attn(
    const u16* __restrict__ Qr, const u16* __restrict__ Kr,
    const u16* __restrict__ Vt, u16* __restrict__ AO) {
  __shared__ u16 smem[34816];
  u16* Kbuf[2];
  u16* Vbuf[2];
  Kbuf[0] = smem;          Vbuf[0] = smem + 8192;
  Kbuf[1] = smem + 16384;  Vbuf[1] = smem + 24576;

  const int qt = blockIdx.x, hd = blockIdx.y, b = blockIdx.z;
  const int kvh = hd >> 2;
  const int tid = threadIdx.x, wid = tid >> 6;
  const int l31 = tid & 31, h = (tid >> 5) & 1;
  const bool hi = h != 0;

  const u16* qp = Qr + (((size_t)(b * 16 + hd) * 2048) + qt * 256 + wid * 32 + l31) * 128;
  const u16* kp = Kr + ((size_t)(b * 4 + kvh) * 2048) * 128;
  const u16* vp = Vt + ((size_t)(b * 4 + kvh) * 128) * 2048;

  bf16x8 qf[8];
#pragma unroll
  for (int ds = 0; ds < 8; ++ds)
    qf[ds] = *(const bf16x8*)(qp + 16 * ds + 8 * h);

  f32x16 oacc[4];
#pragma unroll
  for (int dt = 0; dt < 4; ++dt)
#pragma unroll
    for (int r = 0; r < 16; ++r) oacc[dt][r] = 0.f;
  float mrun = -1e30f, lrun = 0.f;

#define STAGE_KV(KB, DK, DV)                                                   \
  {                                                                            \
    _Pragma("unroll") for (int j = 0; j < 2; ++j) {                            \
      int c = j * 512 + tid;                                                   \
      int rk = c >> 4, gk = (c & 15) ^ (rk & 7);                               \
      gload16(kp + (size_t)((KB) + rk) * 128 + gk * 8,                         \
              (DK) + (j * 512 + wid * 64) * 8);                                \
      int rv = c >> 3, gv = (c & 7) ^ (rv & 7);                                \
      gload16(vp + (size_t)rv * 2048 + (KB) + gv * 8,                          \
              (DV) + (j * 512 + wid * 64) * 8);                                \
    }                                                                          \
  }

  STAGE_KV(0, Kbuf[0], Vbuf[0]);
  __syncthreads();

  int cur = 0;
  for (int kb = 0; kb < 2048; kb += 64) {
    const u16* Kb = Kbuf[cur];
    const u16* Vb = Vbuf[cur];
    if (kb + 64 < 2048) STAGE_KV(kb + 64, Kbuf[cur ^ 1], Vbuf[cur ^ 1]);

    f32x16 s0, s1;
#pragma unroll
    for (int r = 0; r < 16; ++r) { s0[r] = 0.f; s1[r] = 0.f; }
    const int key0 = l31, key1 = 32 + l31;
#pragma unroll
    for (int ds = 0; ds < 8; ++ds) {
      bf16x8 kf0 = *(const bf16x8*)&Kb[key0 * 128 + (((2 * ds + h) ^ (key0 & 7)) * 8)];
      s0 = __builtin_amdgcn_mfma_f32_32x32x16_bf16(kf0, qf[ds], s0, 0, 0, 0);
      bf16x8 kf1 = *(const bf16x8*)&Kb[key1 * 128 + (((2 * ds + h) ^ (key1 & 7)) * 8)];
      s1 = __builtin_amdgcn_mfma_f32_32x32x16_bf16(kf1, qf[ds], s1, 0, 0, 0);
    }

    float pm = -1e30f;
#pragma unroll
    for (int r = 0; r < 16; ++r) pm = fmaxf(pm, fmaxf(s0[r], s1[r]));
    pm = fmaxf(pm, __shfl_xor(pm, 32, 64));
    if (!__all(pm <= mrun + 8.f)) {
      float mn = fmaxf(mrun, pm);
      float sc = __expf(mrun - mn);
      mrun = mn;
      lrun *= sc;
#pragma unroll
      for (int dt = 0; dt < 4; ++dt)
#pragma unroll
        for (int r = 0; r < 16; ++r) oacc[dt][r] *= sc;
    }
    float ls = 0.f;
#pragma unroll
    for (int r = 0; r < 16; ++r) { s0[r] = __expf(s0[r] - mrun); ls += s0[r]; }
#pragma unroll
    for (int r = 0; r < 16; ++r) { s1[r] = __expf(s1[r] - mrun); ls += s1[r]; }
    ls += __shfl_xor(ls, 32, 64);
    lrun += ls;

    unsigned c[16];
#pragma unroll
    for (int j = 0; j < 8; ++j) {
      asm("v_cvt_pk_bf16_f32 %0, %1, %2" : "=v"(c[j]) : "v"(s0[2 * j]), "v"(s0[2 * j + 1]));
      asm("v_cvt_pk_bf16_f32 %0, %1, %2" : "=v"(c[8 + j]) : "v"(s1[2 * j]), "v"(s1[2 * j + 1]));
    }

#pragma unroll
    for (int st = 0; st < 4; ++st) {
      unsigned w0 = sx32(c[4 * st + 0]);
      unsigned w1 = sx32(c[4 * st + 1]);
      unsigned w2 = sx32(c[4 * st + 2]);
      unsigned w3 = sx32(c[4 * st + 3]);
      u32x4 pw;
      pw.x = hi ? w2 : c[4 * st + 0];
      pw.y = hi ? w3 : c[4 * st + 1];
      pw.z = hi ? c[4 * st + 2] : w0;
      pw.w = hi ? c[4 * st + 3] : w1;
      union { u32x4 u; bf16x8 bf; } pc;
      pc.u = pw;
#pragma unroll
      for (int dt = 0; dt < 4; ++dt) {
        int d = 32 * dt + l31;
        bf16x8 vf = *(const bf16x8*)&Vb[d * 64 + (((2 * st + h) ^ (d & 7)) * 8)];
        oacc[dt] = __builtin_amdgcn_mfma_f32_32x32x16_bf16(vf, pc.bf, oacc[dt], 0, 0, 0);
      }
    }
    __syncthreads();
    cur ^= 1;
  }

  u16* Os = smem;
  const float inv = 1.0f / lrun;
  const int q = wid * 32 + l31;
#pragma unroll
  for (int dt = 0; dt < 4; ++dt)
#pragma unroll
    for (int a = 0; a < 4; ++a) {
      int d = 32 * dt + 8 * a + 4 * h;
      ushort4 w;
      w.x = f2bf(oacc[dt][4 * a + 0] * inv);
      w.y = f2bf(oacc[dt][4 * a + 1] * inv);
      w.z = f2bf(oacc[dt][4 * a + 2] * inv);
      w.w = f2bf(oacc[dt][4 * a + 3] * inv);
      *(ushort4*)&Os[q * 136 + d] = w;
    }
  __syncthreads();
  const size_t orow = (size_t)b * 2048 + qt * 256;
#pragma unroll
  for (int rep = 0; rep < 8; ++rep) {
    int idx = rep * 512 + tid;
    int qq = idx >> 4, g = idx & 15;
    us8 v = *(const us8*)&Os[qq * 136 + g * 8];
    *(us8*)&AO[(orow + qq) * 2048 + hd * 128 + g * 8] = v;
  }
#undef STAGE_KV
}

// ---------------------------------------------------------------------------
extern "C" void kernel_launch(void* const* d_in, const int* in_sizes, int n_in,
                              void* d_out, int out_size, void* d_ws, size_t ws_size,
                              hipStream_t stream) {
  const float* x  = (const float*)d_in[0];
  const float* fc = (const float*)d_in[1];
  const float* Wq = (const float*)d_in[2];
  const float* Wk = (const float*)d_in[3];
  const float* Wv = (const float*)d_in[4];
  const float* Wo = (const float*)d_in[5];
  const int* mid  = (const int*)d_in[6];
  float* out = (float*)d_out;
  char* ws = (char*)d_ws;

  // ws layout (bytes)
  u16* XBF  = (u16*)(ws);                 // 4096x2048 bf16        16.8MB
  u16* WCT  = (u16*)(ws + 16777216);      // [2][3072][2048] bf16  25.2MB
  u16* WOT  = (u16*)(ws + 41943040);      // [2][2048][2048] bf16  16.8MB
  u16* QKVs = (u16*)(ws + 58720256);      // [4096][3072] bf16     25.2MB
  u16* QR   = (u16*)(ws + 83886080);      // [2][16][2048][128]    16.8MB
  u16* KR   = (u16*)(ws + 100663296);     // [2][4][2048][128]      4.2MB
  u16* VT   = (u16*)(ws + 104857600);     // [2][4][128][2048]      4.2MB
  u16* AO   = (u16*)(ws + 109051904);     // [4096][2048]          16.8MB
  int* perm = (int*)(ws + 125829120);     // 4096 ints
  int* inv  = (int*)(ws + 125845504);     // 4096 ints
  int* cnt  = (int*)(ws + 125861888);     // 4 ints
  if (ws_size < 150994944) return;        // known-good guard from R1/R2

  wprep<<<dim3(64, 64, 8), dim3(256), 0, stream>>>(Wq, Wk, Wv, Wo, WCT, WOT);
  xcast<<<dim3(4096), dim3(256), 0, stream>>>(x, XBF);
  scount<<<dim3(1), dim3(256), 0, stream>>>(mid, cnt);
  sscatter<<<dim3(16), dim3(256), 0, stream>>>(mid, cnt, perm, inv);
  gemm_qkv<<<dim3(24, 66), dim3(256), 0, stream>>>(XBF, WCT, QKVs, cnt, perm);
  rope_select<<<dim3(4096), dim3(256), 0, stream>>>(QKVs, perm, fc, QR, KR);
  vtrans<<<dim3(64, 16, 2), dim3(256), 0, stream>>>(QKVs, inv, VT);
  attn<<<dim3(8, 16, 2), dim3(512), 0, stream>>>(QR, KR, VT, AO);
  gemm_out<<<dim3(16, 66), dim3(256), 0, stream>>>(AO, WOT, cnt, perm, out);
}

// Round 6
// 505.870 us; speedup vs baseline: 1.2442x; 1.2442x over previous
//
#include <hip/hip_runtime.h>
#include <hip/hip_bf16.h>
#include <stdint.h>

typedef unsigned short u16;
typedef __attribute__((ext_vector_type(8))) __bf16 bf16x8;
typedef __attribute__((ext_vector_type(4))) float f32x4;
typedef __attribute__((ext_vector_type(16))) float f32x16;
typedef __attribute__((ext_vector_type(8))) u16 us8;
typedef __attribute__((ext_vector_type(4))) unsigned u32x4;

#define QSCALE 0.08838834764831843f

__device__ __forceinline__ u16 f2bf(float f) {
  unsigned u = __float_as_uint(f);
  u += 0x7fffu + ((u >> 16) & 1u);
  return (u16)(u >> 16);
}
__device__ __forceinline__ float bf2f(u16 h) {
  return __uint_as_float(((unsigned)h) << 16);
}
// async global->LDS, 16B per lane. lds dst must be wave-uniform base (HW adds lane*16).
__device__ __forceinline__ void gload16(const void* g, void* l) {
  __builtin_amdgcn_global_load_lds(
      (const __attribute__((address_space(1))) unsigned int*)g,
      (__attribute__((address_space(3))) unsigned int*)l, 16, 0, 0);
}
__device__ __forceinline__ unsigned sx32(unsigned v) {
  return (unsigned)__shfl_xor((int)v, 32, 64);
}

// ---------------------------------------------------------------------------
// P1: weight prep -> bf16 [outcol][k] layouts.
// WCT layout: [m][3072][2048] where cols 0-2047=Q, 2048-2559=K_sum, 2560-3071=V_sum.
// WOT layout: [m][2048][2048].
// ---------------------------------------------------------------------------
__global__ __launch_bounds__(256) void wprep(
    const float* __restrict__ Wq, const float* __restrict__ Wk,
    const float* __restrict__ Wv, const float* __restrict__ Wo,
    u16* __restrict__ WCT, u16* __restrict__ WOT) {
  const int sec = blockIdx.z;
  const float* s0;
  const float* s1 = nullptr;
  u16* dst;
  int N;
  switch (sec) {
    case 0: s0 = Wq;                 dst = WCT;                    N = 2048; break;
    case 1: s0 = Wq + 2048*2048;     dst = WCT + (size_t)3072*2048; N = 2048; break;
    case 2: s0 = Wk;                 s1 = Wk + 2048*512;  dst = WCT + (size_t)2048*2048; N = 512; break;
    case 3: s0 = Wk + 2*2048*512;    s1 = Wk + 3*2048*512; dst = WCT + (size_t)5120*2048; N = 512; break;
    case 4: s0 = Wv;                 s1 = Wv + 2048*512;  dst = WCT + (size_t)2560*2048; N = 512; break;
    case 5: s0 = Wv + 2*2048*512;    s1 = Wv + 3*2048*512; dst = WCT + (size_t)5632*2048; N = 512; break;
    case 6: s0 = Wo;                 dst = WOT;                    N = 2048; break;
    default: s0 = Wo + 2048*2048;    dst = WOT + (size_t)2048*2048; N = 2048; break;
  }
  const int n0 = blockIdx.x * 32;
  if (n0 >= N) return;
  const int k0 = blockIdx.y * 32;
  __shared__ float tile[32][33];
  const int tx = threadIdx.x & 31, ty = threadIdx.x >> 5;
#pragma unroll
  for (int i = 0; i < 4; ++i) {
    int k = k0 + ty + 8 * i;
    float v = s0[(size_t)k * N + n0 + tx];
    if (s1) v += s1[(size_t)k * N + n0 + tx];
    tile[ty + 8 * i][tx] = v;
  }
  __syncthreads();
#pragma unroll
  for (int i = 0; i < 4; ++i) {
    int n = n0 + ty + 8 * i;
    dst[(size_t)n * 2048 + k0 + tx] = f2bf(tile[tx][ty + 8 * i]);
  }
}

// ---------------------------------------------------------------------------
// P2: x f32 -> bf16
// ---------------------------------------------------------------------------
__global__ __launch_bounds__(256) void xcast(const float* __restrict__ x,
                                             u16* __restrict__ Xbf) {
  size_t base = ((size_t)blockIdx.x * 256 + threadIdx.x) * 8;
  float4 a = *(const float4*)&x[base];
  float4 c = *(const float4*)&x[base + 4];
  us8 o;
  o[0] = f2bf(a.x); o[1] = f2bf(a.y); o[2] = f2bf(a.z); o[3] = f2bf(a.w);
  o[4] = f2bf(c.x); o[5] = f2bf(c.y); o[6] = f2bf(c.z); o[7] = f2bf(c.w);
  *(us8*)&Xbf[base] = o;
}

// ---------------------------------------------------------------------------
// S1: count modality-0 tokens; init scatter counters.
// ---------------------------------------------------------------------------
__global__ __launch_bounds__(256) void scount(const int* __restrict__ mid,
                                              int* __restrict__ cnt) {
  __shared__ int sh[256];
  int s = 0;
  for (int i = threadIdx.x; i < 4096; i += 256) s += (mid[i] == 0);
  sh[threadIdx.x] = s;
  __syncthreads();
  for (int o = 128; o; o >>= 1) {
    if (threadIdx.x < o) sh[threadIdx.x] += sh[threadIdx.x + o];
    __syncthreads();
  }
  if (threadIdx.x == 0) { cnt[0] = sh[0]; cnt[1] = 0; cnt[2] = 0; }
}

// ---------------------------------------------------------------------------
// S2: scatter tokens into modality buckets. perm[sorted]=token, inv[token]=sorted.
// ---------------------------------------------------------------------------
__global__ __launch_bounds__(256) void sscatter(const int* __restrict__ mid,
                                                int* __restrict__ cnt,
                                                int* __restrict__ perm,
                                                int* __restrict__ inv) {
  int t = blockIdx.x * 256 + threadIdx.x;
  int m = mid[t];
  int base = m ? cnt[0] : 0;
  int pos = base + atomicAdd(&cnt[1 + m], 1);
  perm[pos] = t;
  inv[t] = pos;
}

// ---------------------------------------------------------------------------
// G1: QKV projection over sorted tokens. NO XCD swizzle (holey grid: R4's swizzle
// concentrated live blocks on 4/8 XCDs -> 2x slowdown). Segments interleaved:
// by&1 = segment, by>>1 = row-tile within segment (33 per seg); dead tiles spread
// across XCDs in raw bid order (runs of 24 bids = 3/XCD).
// ---------------------------------------------------------------------------
__global__ __launch_bounds__(256) void gemm_qkv(
    const u16* __restrict__ A, const u16* __restrict__ W, u16* __restrict__ Cq,
    const int* __restrict__ cnt, const int* __restrict__ perm) {
  __shared__ u16 As[128 * 32];
  __shared__ u16 Bs[128 * 32];
  const int n0 = cnt[0];
  const int bx = blockIdx.x, by = blockIdx.y;
  const int seg = by & 1, tile = by >> 1;
  int r0, rend;
  if (seg == 0) { r0 = tile * 128; rend = n0; }
  else          { r0 = n0 + tile * 128; rend = 4096; }
  if (r0 >= rend) return;
  const int col0 = bx * 128;
  const int tid = threadIdx.x, wid = tid >> 6, lane = tid & 63;
  const int lr = lane & 15, lg = lane >> 4;
  const int wr = wid >> 1, wc = wid & 1;
  const u16* W0 = W + ((size_t)seg * 3072 + col0) * 2048;
  const int ra = tid >> 2, gA = tid & 3;
  int ti0 = r0 + ra;      if (ti0 > rend - 1) ti0 = rend - 1;
  int ti1 = r0 + 64 + ra; if (ti1 > rend - 1) ti1 = rend - 1;
  const u16* Ar0 = A + (size_t)perm[ti0] * 2048;
  const u16* Ar1 = A + (size_t)perm[ti1] * 2048;
  const u16* Br0 = W0 + (size_t)ra * 2048;
  const u16* Br1 = W0 + (size_t)(64 + ra) * 2048;

  f32x4 acc[4][4];
#pragma unroll
  for (int m = 0; m < 4; ++m)
#pragma unroll
    for (int n = 0; n < 4; ++n)
#pragma unroll
      for (int r = 0; r < 4; ++r) acc[m][n][r] = 0.f;

  for (int k0 = 0; k0 < 2048; k0 += 32) {
    gload16(Ar0 + k0 + gA * 8, &As[(0 * 256 + wid * 64) * 8]);
    gload16(Br0 + k0 + gA * 8, &Bs[(0 * 256 + wid * 64) * 8]);
    gload16(Ar1 + k0 + gA * 8, &As[(1 * 256 + wid * 64) * 8]);
    gload16(Br1 + k0 + gA * 8, &Bs[(1 * 256 + wid * 64) * 8]);
    __syncthreads();
    bf16x8 af[4], bfr[4];
#pragma unroll
    for (int m = 0; m < 4; ++m)
      af[m] = *(const bf16x8*)&As[(64 * wr + 16 * m + lr) * 32 + 8 * lg];
#pragma unroll
    for (int n = 0; n < 4; ++n)
      bfr[n] = *(const bf16x8*)&Bs[(64 * wc + 16 * n + lr) * 32 + 8 * lg];
#pragma unroll
    for (int m = 0; m < 4; ++m)
#pragma unroll
      for (int n = 0; n < 4; ++n)
        acc[m][n] = __builtin_amdgcn_mfma_f32_16x16x32_bf16(af[m], bfr[n], acc[m][n], 0, 0, 0);
    __syncthreads();
  }
#pragma unroll
  for (int m = 0; m < 4; ++m)
#pragma unroll
    for (int n = 0; n < 4; ++n)
#pragma unroll
      for (int r = 0; r < 4; ++r) {
        int grow = r0 + 64 * wr + 16 * m + 4 * lg + r;
        if (grow < rend) {
          int gcol = col0 + 64 * wc + 16 * n + lr;
          Cq[(size_t)grow * 3072 + gcol] = f2bf(acc[m][n][r]);
        }
      }
}

// ---------------------------------------------------------------------------
// G2: O-projection over sorted tokens. Same dispatch fix as G1.
// ---------------------------------------------------------------------------
__global__ __launch_bounds__(256) void gemm_out(
    const u16* __restrict__ A, const u16* __restrict__ W,
    const int* __restrict__ cnt, const int* __restrict__ perm,
    float* __restrict__ out) {
  __shared__ u16 As[128 * 32];
  __shared__ u16 Bs[128 * 32];
  const int n0 = cnt[0];
  const int bx = blockIdx.x, by = blockIdx.y;
  const int seg = by & 1, tile = by >> 1;
  int r0, rend;
  if (seg == 0) { r0 = tile * 128; rend = n0; }
  else          { r0 = n0 + tile * 128; rend = 4096; }
  if (r0 >= rend) return;
  const int col0 = bx * 128;
  const int tid = threadIdx.x, wid = tid >> 6, lane = tid & 63;
  const int lr = lane & 15, lg = lane >> 4;
  const int wr = wid >> 1, wc = wid & 1;
  const u16* W0 = W + ((size_t)seg * 2048 + col0) * 2048;
  const int ra = tid >> 2, gA = tid & 3;
  int ti0 = r0 + ra;      if (ti0 > rend - 1) ti0 = rend - 1;
  int ti1 = r0 + 64 + ra; if (ti1 > rend - 1) ti1 = rend - 1;
  const u16* Ar0 = A + (size_t)perm[ti0] * 2048;
  const u16* Ar1 = A + (size_t)perm[ti1] * 2048;
  const u16* Br0 = W0 + (size_t)ra * 2048;
  const u16* Br1 = W0 + (size_t)(64 + ra) * 2048;

  f32x4 acc[4][4];
#pragma unroll
  for (int m = 0; m < 4; ++m)
#pragma unroll
    for (int n = 0; n < 4; ++n)
#pragma unroll
      for (int r = 0; r < 4; ++r) acc[m][n][r] = 0.f;

  for (int k0 = 0; k0 < 2048; k0 += 32) {
    gload16(Ar0 + k0 + gA * 8, &As[(0 * 256 + wid * 64) * 8]);
    gload16(Br0 + k0 + gA * 8, &Bs[(0 * 256 + wid * 64) * 8]);
    gload16(Ar1 + k0 + gA * 8, &As[(1 * 256 + wid * 64) * 8]);
    gload16(Br1 + k0 + gA * 8, &Bs[(1 * 256 + wid * 64) * 8]);
    __syncthreads();
    bf16x8 af[4], bfr[4];
#pragma unroll
    for (int m = 0; m < 4; ++m)
      af[m] = *(const bf16x8*)&As[(64 * wr + 16 * m + lr) * 32 + 8 * lg];
#pragma unroll
    for (int n = 0; n < 4; ++n)
      bfr[n] = *(const bf16x8*)&Bs[(64 * wc + 16 * n + lr) * 32 + 8 * lg];
#pragma unroll
    for (int m = 0; m < 4; ++m)
#pragma unroll
      for (int n = 0; n < 4; ++n)
        acc[m][n] = __builtin_amdgcn_mfma_f32_16x16x32_bf16(af[m], bfr[n], acc[m][n], 0, 0, 0);
    __syncthreads();
  }
#pragma unroll
  for (int m = 0; m < 4; ++m)
#pragma unroll
    for (int r = 0; r < 4; ++r) {
      int grow = r0 + 64 * wr + 16 * m + 4 * lg + r;
      if (grow < rend) {
        int tok = perm[grow];
#pragma unroll
        for (int n = 0; n < 4; ++n) {
          int gcol = col0 + 64 * wc + 16 * n + lr;
          out[(size_t)tok * 2048 + gcol] = acc[m][n][r];
        }
      }
    }
}

// ---------------------------------------------------------------------------
// A0: RoPE for Q (scaled) and K over sorted rows; writes token-order layouts.
// ---------------------------------------------------------------------------
__global__ __launch_bounds__(256) void rope_select(
    const u16* __restrict__ QKVs, const int* __restrict__ perm,
    const float* __restrict__ fc, u16* __restrict__ Qr, u16* __restrict__ Kr) {
  const int i = blockIdx.x;
  const int t = perm[i];
  const int b = t >> 11, s = t & 2047;
  __shared__ float Fs[256];
  Fs[threadIdx.x] = fc[(size_t)s * 256 + threadIdx.x];
  __syncthreads();
  const int tid = threadIdx.x;
  {  // Q: 1024 pairs, 4/thread
    int p0 = tid * 4;
    int h = p0 >> 6, ph0 = p0 & 63;
    const u16* src = QKVs + (size_t)i * 3072 + h * 128 + 2 * ph0;
    us8 v = *(const us8*)src;
    us8 o;
#pragma unroll
    for (int j = 0; j < 4; ++j) {
      float x0 = bf2f(v[2 * j]), x1 = bf2f(v[2 * j + 1]);
      const float* F = &Fs[(ph0 + j) * 4];
      o[2 * j]     = f2bf((x0 * F[0] + x1 * F[2]) * QSCALE);
      o[2 * j + 1] = f2bf((x0 * F[1] + x1 * F[3]) * QSCALE);
    }
    *(us8*)(Qr + (((size_t)(b * 16 + h) * 2048) + s) * 128 + 2 * ph0) = o;
  }
  if (tid < 64) {  // K: 256 pairs, 4/thread
    int p0 = tid * 4;
    int kh = p0 >> 6, ph0 = p0 & 63;
    const u16* src = QKVs + (size_t)i * 3072 + 2048 + kh * 128 + 2 * ph0;
    us8 v = *(const us8*)src;
    us8 o;
#pragma unroll
    for (int j = 0; j < 4; ++j) {
      float x0 = bf2f(v[2 * j]), x1 = bf2f(v[2 * j + 1]);
      const float* F = &Fs[(ph0 + j) * 4];
      o[2 * j]     = f2bf(x0 * F[0] + x1 * F[2]);
      o[2 * j + 1] = f2bf(x0 * F[1] + x1 * F[3]);
    }
    *(us8*)(Kr + (((size_t)(b * 4 + kh) * 2048) + s) * 128 + 2 * ph0) = o;
  }
}

// ---------------------------------------------------------------------------
// A1: V transpose -> Vt [b][kv][d][s] bf16 (reads sorted QKVs rows via inv)
// ---------------------------------------------------------------------------
__global__ __launch_bounds__(256) void vtrans(
    const u16* __restrict__ QKVs, const int* __restrict__ inv, u16* __restrict__ Vt) {
  __shared__ u16 tilebuf[32][34];
  const int s0 = blockIdx.x * 32, d0 = blockIdx.y * 32, b = blockIdx.z;
  const int tx = threadIdx.x & 31, ty = threadIdx.x >> 5;
#pragma unroll
  for (int i = 0; i < 4; ++i) {
    int s = s0 + ty + 8 * i;
    int row = inv[b * 2048 + s];
    tilebuf[ty + 8 * i][tx] = QKVs[(size_t)row * 3072 + 2560 + d0 + tx];
  }
  __syncthreads();
#pragma unroll
  for (int i = 0; i < 4; ++i) {
    int d = d0 + ty + 8 * i;
    Vt[(((size_t)(b * 4 + (d >> 7)) * 128) + (d & 127)) * 2048 + s0 + tx] =
        tilebuf[tx][ty + 8 * i];
  }
}

// ---------------------------------------------------------------------------
// A2: flash attention (unchanged from R2): 8 waves x 32 q-rows, 32x32x16 MFMA,
// swapped QK^T, O^T PV, K/V LDS double-buffer, XOR-swizzled b128.
// ---------------------------------------------------------------------------
__global__ __launch_bounds__(512, 2) void attn(
    const u16* __restrict__ Qr, const u16* __restrict__ Kr,
    const u16* __restrict__ Vt, u16* __restrict__ AO) {
  __shared__ u16 smem[34816];
  u16* Kbuf[2];
  u16* Vbuf[2];
  Kbuf[0] = smem;          Vbuf[0] = smem + 8192;
  Kbuf[1] = smem + 16384;  Vbuf[1] = smem + 24576;

  const int qt = blockIdx.x, hd = blockIdx.y, b = blockIdx.z;
  const int kvh = hd >> 2;
  const int tid = threadIdx.x, wid = tid >> 6;
  const int l31 = tid & 31, h = (tid >> 5) & 1;
  const bool hi = h != 0;

  const u16* qp = Qr + (((size_t)(b * 16 + hd) * 2048) + qt * 256 + wid * 32 + l31) * 128;
  const u16* kp = Kr + ((size_t)(b * 4 + kvh) * 2048) * 128;
  const u16* vp = Vt + ((size_t)(b * 4 + kvh) * 128) * 2048;

  bf16x8 qf[8];
#pragma unroll
  for (int ds = 0; ds < 8; ++ds)
    qf[ds] = *(const bf16x8*)(qp + 16 * ds + 8 * h);

  f32x16 oacc[4];
#pragma unroll
  for (int dt = 0; dt < 4; ++dt)
#pragma unroll
    for (int r = 0; r < 16; ++r) oacc[dt][r] = 0.f;
  float mrun = -1e30f, lrun = 0.f;

#define STAGE_KV(KB, DK, DV)                                                   \
  {                                                                            \
    _Pragma("unroll") for (int j = 0; j < 2; ++j) {                            \
      int c = j * 512 + tid;                                                   \
      int rk = c >> 4, gk = (c & 15) ^ (rk & 7);                               \
      gload16(kp + (size_t)((KB) + rk) * 128 + gk * 8,                         \
              (DK) + (j * 512 + wid * 64) * 8);                                \
      int rv = c >> 3, gv = (c & 7) ^ (rv & 7);                                \
      gload16(vp + (size_t)rv * 2048 + (KB) + gv * 8,                          \
              (DV) + (j * 512 + wid * 64) * 8);                                \
    }                                                                          \
  }

  STAGE_KV(0, Kbuf[0], Vbuf[0]);
  __syncthreads();

  int cur = 0;
  for (int kb = 0; kb < 2048; kb += 64) {
    const u16* Kb = Kbuf[cur];
    const u16* Vb = Vbuf[cur];
    if (kb + 64 < 2048) STAGE_KV(kb + 64, Kbuf[cur ^ 1], Vbuf[cur ^ 1]);

    f32x16 s0, s1;
#pragma unroll
    for (int r = 0; r < 16; ++r) { s0[r] = 0.f; s1[r] = 0.f; }
    const int key0 = l31, key1 = 32 + l31;
#pragma unroll
    for (int ds = 0; ds < 8; ++ds) {
      bf16x8 kf0 = *(const bf16x8*)&Kb[key0 * 128 + (((2 * ds + h) ^ (key0 & 7)) * 8)];
      s0 = __builtin_amdgcn_mfma_f32_32x32x16_bf16(kf0, qf[ds], s0, 0, 0, 0);
      bf16x8 kf1 = *(const bf16x8*)&Kb[key1 * 128 + (((2 * ds + h) ^ (key1 & 7)) * 8)];
      s1 = __builtin_amdgcn_mfma_f32_32x32x16_bf16(kf1, qf[ds], s1, 0, 0, 0);
    }

    float pm = -1e30f;
#pragma unroll
    for (int r = 0; r < 16; ++r) pm = fmaxf(pm, fmaxf(s0[r], s1[r]));
    pm = fmaxf(pm, __shfl_xor(pm, 32, 64));
    if (!__all(pm <= mrun + 8.f)) {
      float mn = fmaxf(mrun, pm);
      float sc = __expf(mrun - mn);
      mrun = mn;
      lrun *= sc;
#pragma unroll
      for (int dt = 0; dt < 4; ++dt)
#pragma unroll
        for (int r = 0; r < 16; ++r) oacc[dt][r] *= sc;
    }
    float ls = 0.f;
#pragma unroll
    for (int r = 0; r < 16; ++r) { s0[r] = __expf(s0[r] - mrun); ls += s0[r]; }
#pragma unroll
    for (int r = 0; r < 16; ++r) { s1[r] = __expf(s1[r] - mrun); ls += s1[r]; }
    ls += __shfl_xor(ls, 32, 64);
    lrun += ls;

    unsigned c[16];
#pragma unroll
    for (int j = 0; j < 8; ++j) {
      asm("v_cvt_pk_bf16_f32 %0, %1, %2" : "=v"(c[j]) : "v"(s0[2 * j]), "v"(s0[2 * j + 1]));
      asm("v_cvt_pk_bf16_f32 %0, %1, %2" : "=v"(c[8 + j]) : "v"(s1[2 * j]), "v"(s1[2 * j + 1]));
    }

#pragma unroll
    for (int st = 0; st < 4; ++st) {
      unsigned w0 = sx32(c[4 * st + 0]);
      unsigned w1 = sx32(c[4 * st + 1]);
      unsigned w2 = sx32(c[4 * st + 2]);
      unsigned w3 = sx32(c[4 * st + 3]);
      u32x4 pw;
      pw.x = hi ? w2 : c[4 * st + 0];
      pw.y = hi ? w3 : c[4 * st + 1];
      pw.z = hi ? c[4 * st + 2] : w0;
      pw.w = hi ? c[4 * st + 3] : w1;
      union { u32x4 u; bf16x8 bf; } pc;
      pc.u = pw;
#pragma unroll
      for (int dt = 0; dt < 4; ++dt) {
        int d = 32 * dt + l31;
        bf16x8 vf = *(const bf16x8*)&Vb[d * 64 + (((2 * st + h) ^ (d & 7)) * 8)];
        oacc[dt] = __builtin_amdgcn_mfma_f32_32x32x16_bf16(vf, pc.bf, oacc[dt], 0, 0, 0);
      }
    }
    __syncthreads();
    cur ^= 1;
  }

  u16* Os = smem;
  const float inv = 1.0f / lrun;
  const int q = wid * 32 + l31;
#pragma unroll
  for (int dt = 0; dt < 4; ++dt)
#pragma unroll
    for (int a = 0; a < 4; ++a) {
      int d = 32 * dt + 8 * a + 4 * h;
      ushort4 w;
      w.x = f2bf(oacc[dt][4 * a + 0] * inv);
      w.y = f2bf(oacc[dt][4 * a + 1] * inv);
      w.z = f2bf(oacc[dt][4 * a + 2] * inv);
      w.w = f2bf(oacc[dt][4 * a + 3] * inv);
      *(ushort4*)&Os[q * 136 + d] = w;
    }
  __syncthreads();
  const size_t orow = (size_t)b * 2048 + qt * 256;
#pragma unroll
  for (int rep = 0; rep < 8; ++rep) {
    int idx = rep * 512 + tid;
    int qq = idx >> 4, g = idx & 15;
    us8 v = *(const us8*)&Os[qq * 136 + g * 8];
    *(us8*)&AO[(orow + qq) * 2048 + hd * 128 + g * 8] = v;
  }
#undef STAGE_KV
}

// ---------------------------------------------------------------------------
extern "C" void kernel_launch(void* const* d_in, const int* in_sizes, int n_in,
                              void* d_out, int out_size, void* d_ws, size_t ws_size,
                              hipStream_t stream) {
  const float* x  = (const float*)d_in[0];
  const float* fc = (const float*)d_in[1];
  const float* Wq = (const float*)d_in[2];
  const float* Wk = (const float*)d_in[3];
  const float* Wv = (const float*)d_in[4];
  const float* Wo = (const float*)d_in[5];
  const int* mid  = (const int*)d_in[6];
  float* out = (float*)d_out;
  char* ws = (char*)d_ws;

  // ws layout (bytes)
  u16* XBF  = (u16*)(ws);                 // 4096x2048 bf16        16.8MB
  u16* WCT  = (u16*)(ws + 16777216);      // [2][3072][2048] bf16  25.2MB
  u16* WOT  = (u16*)(ws + 41943040);      // [2][2048][2048] bf16  16.8MB
  u16* QKVs = (u16*)(ws + 58720256);      // [4096][3072] bf16     25.2MB
  u16* QR   = (u16*)(ws + 83886080);      // [2][16][2048][128]    16.8MB
  u16* KR   = (u16*)(ws + 100663296);     // [2][4][2048][128]      4.2MB
  u16* VT   = (u16*)(ws + 104857600);     // [2][4][128][2048]      4.2MB
  u16* AO   = (u16*)(ws + 109051904);     // [4096][2048]          16.8MB
  int* perm = (int*)(ws + 125829120);     // 4096 ints
  int* inv  = (int*)(ws + 125845504);     // 4096 ints
  int* cnt  = (int*)(ws + 125861888);     // 4 ints
  if (ws_size < 150994944) return;

  wprep<<<dim3(64, 64, 8), dim3(256), 0, stream>>>(Wq, Wk, Wv, Wo, WCT, WOT);
  xcast<<<dim3(4096), dim3(256), 0, stream>>>(x, XBF);
  scount<<<dim3(1), dim3(256), 0, stream>>>(mid, cnt);
  sscatter<<<dim3(16), dim3(256), 0, stream>>>(mid, cnt, perm, inv);
  gemm_qkv<<<dim3(24, 66), dim3(256), 0, stream>>>(XBF, WCT, QKVs, cnt, perm);
  rope_select<<<dim3(4096), dim3(256), 0, stream>>>(QKVs, perm, fc, QR, KR);
  vtrans<<<dim3(64, 16, 2), dim3(256), 0, stream>>>(QKVs, inv, VT);
  attn<<<dim3(8, 16, 2), dim3(512), 0, stream>>>(QR, KR, VT, AO);
  gemm_out<<<dim3(16, 66), dim3(256), 0, stream>>>(AO, WOT, cnt, perm, out);
}